// Round 9
// baseline (275.370 us; speedup 1.0000x reference)
//
#include <hip/hip_runtime.h>
#include <stdint.h>

#define NN 6144        // nodes
#define NC 576         // padded V columns (517 used)

typedef float f32x4 __attribute__((ext_vector_type(4)));
typedef __bf16 bf16x8v __attribute__((ext_vector_type(8)));

__device__ __forceinline__ unsigned short f2bf(float f) {
  unsigned u = __float_as_uint(f);
  u += 0x7FFFu + ((u >> 16) & 1u);   // RNE
  return (unsigned short)(u >> 16);
}

__device__ __forceinline__ float bf2f(unsigned short s) {
  unsigned u = (unsigned)s << 16;
  return __uint_as_float(u);
}

// f32 -> OCP e4m3fn, RNE, clamp to +-448
__device__ __forceinline__ unsigned char f2e4m3(float f) {
  unsigned u = __float_as_uint(f);
  unsigned sgn = (u >> 24) & 0x80u;
  unsigned au = u & 0x7FFFFFFFu;
  if (au >= 0x43E00000u) return (unsigned char)(sgn | 0x7E);
  if (au < 0x3C800000u) {
    int q = (int)rintf(__uint_as_float(au) * 512.0f);
    return (unsigned char)(sgn | (q >= 8 ? 0x08 : q));
  }
  unsigned r = au + 0x7FFFFu + ((au >> 20) & 1u);
  int e = (int)(r >> 23) - 127;
  unsigned m = (r >> 20) & 7u;
  return (unsigned char)(sgn | ((unsigned)(e + 7) << 3) | m);
}

__device__ __forceinline__ unsigned short pack2(float a, float b) {
  return (unsigned short)f2e4m3(a) | ((unsigned short)f2e4m3(b) << 8);
}

__device__ __forceinline__ void async_load16(const void* g, void* l) {
  __builtin_amdgcn_global_load_lds(
      (__attribute__((address_space(1))) void*)(uintptr_t)g,
      (__attribute__((address_space(3))) void*)(uint32_t)(uintptr_t)l,
      16, 0, 0);
}

// ---------------- p0s: tiny prep (wsw + Acat + T only; x-conversion fused into k1m) ----
__global__ __launch_bounds__(256) void p0s(
    const float* __restrict__ W,
    const float* __restrict__ Aw, const float* __restrict__ Wb,
    unsigned short* __restrict__ wsw, float* __restrict__ Acat,
    float* __restrict__ T)
{
  const int bid = blockIdx.x, t = threadIdx.x;
  if (bid < 8) {           // wsw: 8192 entries (16 col-tiles x 8 kc x 64 lanes)
#pragma unroll
    for (int i = 0; i < 4; ++i) {
      const int e = bid * 256 + t + i * 2048;
      const int l = e & 63, kc = (e >> 6) & 7, ct = e >> 9;
      const int c = ct * 16 + (l & 15);
      const int h = c >> 6, d0 = c & 63;
      const int ks = kc * 32 + (l >> 4) * 8;
      const float* src = W + h * 16384 + ks * 64 + d0;
      unsigned uu[4];
#pragma unroll
      for (int j = 0; j < 4; ++j)
        uu[j] = (unsigned)f2bf(src[(2*j) * 64]) | ((unsigned)f2bf(src[(2*j+1) * 64]) << 16);
      *(uint4*)(wsw + (size_t)e * 8) = (uint4){uu[0], uu[1], uu[2], uu[3]};
    }
    return;
  }
  // bid == 8: Acat[asv|adv|Wbc], T zero
  T[t] = 0.f;
  const int h = t >> 6, d = t & 63;
  Acat[t]       = Aw[h * 128 + d];
  Acat[256 + t] = Aw[h * 128 + 64 + d];
  Acat[512 + t] = Wb[t];
}

// ---------------- k1m: feature MFMA w/ fused x->bf16 LDS staging (blocks 0..191)
//                  + adj->bitmask pack, coalesced via LDS repack (192..4799) ----
__global__ __launch_bounds__(256) void k1m(
    const float* __restrict__ x, const unsigned short* __restrict__ wsw,
    const float* __restrict__ Acat, const float* __restrict__ Ab,
    const int* __restrict__ adj, unsigned* __restrict__ bm,
    unsigned char* __restrict__ V8, float* __restrict__ e_src, float* __restrict__ T)
{
  // lsh: pack-branch = nibble array (8KB); MFMA-branch = lx (16KB) then lv (4x4KB)
  __shared__ unsigned char lsh[16384];
  __shared__ float lt[256];
  const int t = threadIdx.x;

  if (blockIdx.x >= 192) {   // ---- pack: adj int32 -> 1-bit mask, coalesced ----
    const int pb = blockIdx.x - 192;            // 0..4607; block covers 8192 ints
    const int4* src = (const int4*)adj + (size_t)pb * 2048;
    unsigned char* ln = lsh;                    // 2048 nibble-bytes
#pragma unroll
    for (int i = 0; i < 8; ++i) {               // lane-contiguous 16B loads (1KB/instr)
      int4 q = src[t + i * 256];
      unsigned nib = (unsigned)q.x | ((unsigned)q.y << 1) |
                     ((unsigned)q.z << 2) | ((unsigned)q.w << 3);
      ln[t + i * 256] = (unsigned char)nib;
    }
    __syncthreads();
    const uint2 b2 = *(const uint2*)(ln + t * 8);   // 8 nibbles for word t
    unsigned pl = (b2.x | (b2.x >> 4)) & 0x00FF00FFu; pl = (pl | (pl >> 8)) & 0xFFFFu;
    unsigned ph = (b2.y | (b2.y >> 4)) & 0x00FF00FFu; ph = (ph | (ph >> 8)) & 0xFFFFu;
    bm[pb * 256 + t] = pl | (ph << 16);
    return;
  }

  // ---- k1-part: block covers nodes 32b..32b+31 (waves 0,1: tile0; 2,3: tile1) ----
  const int w = t >> 6, l = t & 63;
  const int v = blockIdx.x * 4 + w;
  const int mt = v >> 1, nh = v & 1;
  const int i0 = mt * 16, c0 = nh * 128;
  const int lm = l & 15, lk = l >> 4;

  // stage x -> lx in the R10 fragment layout
  {
    unsigned short* lx = (unsigned short*)lsh;
    const float* xb = x + (size_t)(blockIdx.x * 32) * 256;
#pragma unroll
    for (int j = 0; j < 4; ++j) {
      const int e = t + j * 256;
      const int tile = e >> 9, e9 = e & 511;
      const int el = e9 & 63, kc = e9 >> 6;
      const int node = tile * 16 + (el & 15);
      const int ks = kc * 32 + (el >> 4) * 8;
      const float4* xp = (const float4*)(xb + (size_t)node * 256 + ks);
      float4 v0 = xp[0], v1 = xp[1];
      uint4 o;
      o.x = (unsigned)f2bf(v0.x) | ((unsigned)f2bf(v0.y) << 16);
      o.y = (unsigned)f2bf(v0.z) | ((unsigned)f2bf(v0.w) << 16);
      o.z = (unsigned)f2bf(v1.x) | ((unsigned)f2bf(v1.y) << 16);
      o.w = (unsigned)f2bf(v1.z) | ((unsigned)f2bf(v1.w) << 16);
      *(uint4*)(lx + (size_t)e * 8) = o;
    }
  }
  lt[t] = 0.f;
  __syncthreads();

  f32x4 acc[8];
#pragma unroll
  for (int nt = 0; nt < 8; ++nt) acc[nt] = (f32x4){0.f, 0.f, 0.f, 0.f};

  const unsigned short* ap = (const unsigned short*)lsh + (((size_t)(w >> 1)) * 512 + l) * 8;
  const unsigned short* bp = wsw + ((size_t)nh * 4096 + l) * 8;

#pragma unroll
  for (int kc = 0; kc < 8; ++kc) {
    bf16x8v a = *(const bf16x8v*)(ap + (size_t)kc * 512);
#pragma unroll
    for (int nt = 0; nt < 8; ++nt) {
      bf16x8v b = *(const bf16x8v*)(bp + ((size_t)nt * 512 + kc * 64) * 8);
      acc[nt] = __builtin_amdgcn_mfma_f32_16x16x32_bf16(a, b, acc[nt], 0, 0, 0);
    }
  }

  float asv[8], adv[8];
#pragma unroll
  for (int nt = 0; nt < 8; ++nt) {
    const int cc = c0 + nt * 16 + lm;
    const float wb = Acat[512 + cc];
#pragma unroll
    for (int rr = 0; rr < 4; ++rr) acc[nt][rr] += wb;
    asv[nt] = Acat[cc];
    adv[nt] = Acat[256 + cc];
  }

#pragma unroll
  for (int nt = 0; nt < 8; ++nt)
    atomicAdd(&lt[c0 + nt * 16 + lm], acc[nt][0] + acc[nt][1] + acc[nt][2] + acc[nt][3]);

  float ss[2][4], sd[2][4];
#pragma unroll
  for (int hl = 0; hl < 2; ++hl)
#pragma unroll
    for (int rr = 0; rr < 4; ++rr) {
      float s1 = 0.f, s2 = 0.f;
#pragma unroll
      for (int j = 0; j < 4; ++j) {
        s1 += acc[hl * 4 + j][rr] * asv[hl * 4 + j];
        s2 += acc[hl * 4 + j][rr] * adv[hl * 4 + j];
      }
      ss[hl][rr] = s1; sd[hl][rr] = s2;
    }
#pragma unroll
  for (int off = 1; off < 16; off <<= 1)
#pragma unroll
    for (int hl = 0; hl < 2; ++hl)
#pragma unroll
      for (int rr = 0; rr < 4; ++rr) {
        ss[hl][rr] += __shfl_xor(ss[hl][rr], off);
        sd[hl][rr] += __shfl_xor(sd[hl][rr], off);
      }

  float ed[2][4];
#pragma unroll
  for (int hl = 0; hl < 2; ++hl)
#pragma unroll
    for (int rr = 0; rr < 4; ++rr) ed[hl][rr] = expf(sd[hl][rr]);

  if (lm == 0) {
#pragma unroll
    for (int hl = 0; hl < 2; ++hl) {
      const int hh = nh * 2 + hl;
      const float ab = Ab[hh];
#pragma unroll
      for (int rr = 0; rr < 4; ++rr)
        e_src[(size_t)hh * NN + i0 + lk * 4 + rr] = expf(ss[hl][rr] + ab);
    }
  }

  // all waves are done reading lx; lsh becomes lv from here
  __syncthreads();

  unsigned char* mylv = lsh + w * 4096;
#pragma unroll
  for (int nt = 0; nt < 8; ++nt) {
    const int hl = nt >> 2;
    const int d = (nt & 3) * 16 + lm;
    const int lcE = hl * 128 + d;
    const int lcP = lcE + 64;
    *(unsigned short*)(mylv + lcE * 16 + lk * 4)     = pack2(ed[hl][0] * acc[nt][0], ed[hl][1] * acc[nt][1]);
    *(unsigned short*)(mylv + lcE * 16 + lk * 4 + 2) = pack2(ed[hl][2] * acc[nt][2], ed[hl][3] * acc[nt][3]);
    *(unsigned short*)(mylv + lcP * 16 + lk * 4)     = pack2(acc[nt][0], acc[nt][1]);
    *(unsigned short*)(mylv + lcP * 16 + lk * 4 + 2) = pack2(acc[nt][2], acc[nt][3]);
  }
#pragma unroll
  for (int j = 0; j < 4; ++j) {
    const int lc = j * 64 + l;
    uint4 val = *(const uint4*)(mylv + lc * 16);
    *(uint4*)(V8 + (size_t)(nh * 256 + lc) * NN + i0) = val;
  }
  if (lm == 0) {
#pragma unroll
    for (int hl = 0; hl < 2; ++hl) {
      const int hh = nh * 2 + hl;
      unsigned char* pq = V8 + (size_t)(512 + hh) * NN + i0 + lk * 4;
      *(unsigned short*)pq       = pack2(ed[hl][0], ed[hl][1]);
      *(unsigned short*)(pq + 2) = pack2(ed[hl][2], ed[hl][3]);
    }
    if (nh == 0)
      *(unsigned*)(V8 + (size_t)516 * NN + i0 + lk * 4) = 0x38383838u;
  }

  __syncthreads();
  atomicAdd(&T[t], lt[t]);
}

// ---------------- k2 v15b: 3-phase counted-vmcnt pipeline (T3+T4), dbuf, bitmask A.
// B-tile padded to 160 rows -> 5 uniform gload_lds/wave/tile.
// Steady-state per-wave FIFO [b,b,N0,N1 | N2,N3 | N4]; gates P0 vmcnt(3),
// P1 vmcnt(6), P2 vmcnt(6). LAST ITERATION PEELED (no prefetch): FIFO
// [b,b,N0..N4] -> gates vmcnt(3)/vmcnt(2)/vmcnt(0)  [fixes R8 race].
// A bytes 0x08 = 2^-6 e4m3; epilogue x64 (exact).
__global__ __launch_bounds__(256, 3) void k2_gemm(
    const unsigned* __restrict__ bm, const unsigned char* __restrict__ V8,
    unsigned short* __restrict__ out2b, float* __restrict__ out2e, int nks)
{
  __shared__ unsigned char lB[2][160 * 128];
  const int t   = threadIdx.x;
  const int ks  = blockIdx.x / 192;
  const int r   = blockIdx.x - ks * 192;
  const int cb  = r & 3;
  const int rb  = r >> 2;                 // 0..47
  const int krange = NN / nks;
  const int i0 = rb * 128, n0 = cb * 144, k0 = ks * krange;
  const int w = t >> 6, l = t & 63;
  const int lm = l & 15, lk = l >> 4;

  f32x4 acc[2][9];
#pragma unroll
  for (int mt = 0; mt < 2; ++mt)
#pragma unroll
    for (int nt = 0; nt < 9; ++nt) acc[mt][nt] = (f32x4){0.f, 0.f, 0.f, 0.f};

  int scol[5], sgr[5];
#pragma unroll
  for (int u = 0; u < 5; ++u) {
    const int gi = u * 256 + t;
    scol[u] = gi >> 3;
    sgr[u]  = (gi & 7) ^ (scol[u] & 7);
  }

  // per-row bitmask: row stride NN/32 = 192 u32; thread covers k-window lk*32..+31
  const unsigned* gA0 = bm + (size_t)(i0 + w * 32 + lm) * (NN / 32) + (k0 >> 5) + lk;
  const unsigned char* gBb = V8 + (size_t)n0 * NN + k0;

  const int iters = krange / 128;

#define K2_ISSUE(U)                                                             \
  async_load16(gBn + (size_t)scol[U] * NN + sgr[U] * 16,                        \
               dst + (size_t)((U) * 256 + (t & ~63)) * 16)

#define K2_EXPAND                                                               \
  do {                                                                          \
    unsigned bits[2] = {bc0, bc1};                                              \
    _Pragma("unroll")                                                           \
    for (int mtq = 0; mtq < 2; ++mtq) {                                         \
      unsigned u[8];                                                            \
      _Pragma("unroll")                                                         \
      for (int i = 0; i < 8; ++i) {                                             \
        unsigned nib = (bits[mtq] >> (4 * i)) & 0xFu;                           \
        u[i] = ((nib * 0x00204081u) & 0x01010101u) << 3;                        \
      }                                                                         \
      afr[mtq][0].x = (long long)(((unsigned long long)u[1] << 32) | u[0]);     \
      afr[mtq][0].y = (long long)(((unsigned long long)u[3] << 32) | u[2]);     \
      afr[mtq][1].x = (long long)(((unsigned long long)u[5] << 32) | u[4]);     \
      afr[mtq][1].y = (long long)(((unsigned long long)u[7] << 32) | u[6]);     \
    }                                                                           \
  } while (0)

#define K2_MFMA_PHASE(NTB)                                                      \
  __builtin_amdgcn_s_setprio(1);                                                \
  _Pragma("unroll")                                                             \
  for (int b2 = 0; b2 < 2; ++b2) {                                              \
    _Pragma("unroll")                                                           \
    for (int q = 0; q < 3; ++q) {                                               \
      const int cc = ((NTB) + q) * 16 + lm;                                     \
      const int pos = (lk * 2 + b2) ^ (cc & 7);                                 \
      longlong2 bv = *(const longlong2*)(lB[cur] + cc * 128 + pos * 16);        \
      _Pragma("unroll")                                                         \
      for (int mtq = 0; mtq < 2; ++mtq) {                                       \
        acc[mtq][(NTB) + q] = __builtin_amdgcn_mfma_f32_16x16x32_fp8_fp8(       \
            afr[mtq][b2].x, bv.x, acc[mtq][(NTB) + q], 0, 0, 0);                \
        acc[mtq][(NTB) + q] = __builtin_amdgcn_mfma_f32_16x16x32_fp8_fp8(       \
            afr[mtq][b2].y, bv.y, acc[mtq][(NTB) + q], 0, 0, 0);                \
      }                                                                         \
    }                                                                           \
  }                                                                             \
  __builtin_amdgcn_s_setprio(0)

  // ---- prologue: bits0 + full tile0 stage, one-time full drain ----
  unsigned bc0 = gA0[0];
  unsigned bc1 = gA0[16 * (NN / 32)];
  {
    const unsigned char* gBn = gBb;
    unsigned char* dst = (unsigned char*)lB[0];
#pragma unroll
    for (int u = 0; u < 5; ++u) { K2_ISSUE(u); }
  }
  asm volatile("s_waitcnt vmcnt(0)" ::: "memory");
  __syncthreads();

  int cur = 0;
  for (int it = 0; it < iters - 1; ++it) {
    const unsigned char* gBn = gBb + (it + 1) * 128;
    unsigned char* dst = (unsigned char*)lB[cur ^ 1];
    longlong2 afr[2][2];

    // ---- P0: needs N1 of current tile ----
    asm volatile("s_waitcnt vmcnt(3)" ::: "memory");
    __builtin_amdgcn_s_barrier();
    __builtin_amdgcn_sched_barrier(0);
    unsigned bn0 = gA0[(size_t)(it + 1) * 4];
    unsigned bn1 = gA0[16 * (NN / 32) + (size_t)(it + 1) * 4];
    K2_ISSUE(0);
    K2_ISSUE(1);
    K2_EXPAND;
    K2_MFMA_PHASE(0);

    // ---- P1: needs N2 ----
    asm volatile("s_waitcnt vmcnt(6)" ::: "memory");
    __builtin_amdgcn_s_barrier();
    __builtin_amdgcn_sched_barrier(0);
    K2_ISSUE(2);
    K2_ISSUE(3);
    K2_MFMA_PHASE(3);

    // ---- P2: needs N4 ----
    asm volatile("s_waitcnt vmcnt(6)" ::: "memory");
    __builtin_amdgcn_s_barrier();
    __builtin_amdgcn_sched_barrier(0);
    K2_ISSUE(4);
    K2_MFMA_PHASE(6);

    bc0 = bn0; bc1 = bn1;
    cur ^= 1;
  }

  // ---- peeled last iteration: no prefetch; exact gates 3/2/0 ----
  {
    longlong2 afr[2][2];
    asm volatile("s_waitcnt vmcnt(3)" ::: "memory");
    __builtin_amdgcn_s_barrier();
    __builtin_amdgcn_sched_barrier(0);
    K2_EXPAND;
    K2_MFMA_PHASE(0);

    asm volatile("s_waitcnt vmcnt(2)" ::: "memory");
    __builtin_amdgcn_s_barrier();
    __builtin_amdgcn_sched_barrier(0);
    K2_MFMA_PHASE(3);

    asm volatile("s_waitcnt vmcnt(0)" ::: "memory");
    __builtin_amdgcn_s_barrier();
    __builtin_amdgcn_sched_barrier(0);
    K2_MFMA_PHASE(6);
  }
#undef K2_ISSUE
#undef K2_EXPAND
#undef K2_MFMA_PHASE
  __syncthreads();   // all LDS traffic done before epilogue reuse

  // epilogue: x64 undoes the 2^-6 A-scale; per-wave LDS transpose -> panel chunks
  unsigned short* lw = (unsigned short*)((char*)lB[0] + w * 4608);
  float* oe = out2e + (size_t)ks * ((size_t)NN * 64);
  unsigned short* pb = out2b + ((size_t)(ks * 4 + cb) * NN + i0 + w * 32) * 144;
#pragma unroll
  for (int mt = 0; mt < 2; ++mt) {
#pragma unroll
    for (int nt = 0; nt < 9; ++nt) {
      const int coll = nt * 16 + lm;
#pragma unroll
      for (int rr = 0; rr < 4; ++rr)
        lw[(lk * 4 + rr) * 144 + coll] = f2bf(acc[mt][nt][rr] * 64.0f);
      if (cb == 3 && nt >= 5) {
        const int row = i0 + w * 32 + mt * 16 + lk * 4;
#pragma unroll
        for (int rr = 0; rr < 4; ++rr)
          oe[(size_t)(row + rr) * 64 + (n0 + coll - 512)] = acc[mt][nt][rr] * 64.0f;
      }
    }
    const uint4* ls = (const uint4*)((char*)lB[0] + w * 4608);
    char* dst2 = (char*)(pb + (size_t)mt * 16 * 144);
    for (int s = l; s < 288; s += 64)
      *(uint4*)(dst2 + s * 16) = ls[s];
  }
}

// ---------------- k3: combine across nks K-partials (R18-verified) ----------------
__global__ __launch_bounds__(256) void k3_final(
    const unsigned short* __restrict__ out2b, const float* __restrict__ out2e,
    const float* __restrict__ e_src, const float* __restrict__ T,
    float* __restrict__ out, int nks)
{
  const int n = blockIdx.x, c = threadIdx.x;
  const int h = c >> 6, d = c & 63;
  const int cS = h * 128 + d, cP = cS + 64;
  const int cbS = cS / 144, ofS = cS % 144;
  const int cbP = cP / 144, ofP = cP % 144;
  float Se = 0.f, Sp = 0.f, E = 0.f, dg = 0.f;
  for (int s = 0; s < nks; ++s) {
    const unsigned short* base = out2b + (size_t)s * 4 * NN * 144;
    Se += bf2f(base[((size_t)cbS * NN + n) * 144 + ofS]);
    Sp += bf2f(base[((size_t)cbP * NN + n) * 144 + ofP]);
    const float* re = out2e + (size_t)s * NN * 64 + (size_t)n * 64;
    E  += re[h];
    dg += re[4];
  }
  float e = e_src[h * NN + n];
  float D = e * E + ((float)NN - dg);
  out[(size_t)n * 256 + c] = (e * Se + (T[c] - Sp)) / D;
}

extern "C" void kernel_launch(void* const* d_in, const int* in_sizes, int n_in,
                              void* d_out, int out_size, void* d_ws, size_t ws_size,
                              hipStream_t stream) {
  const float* x  = (const float*)d_in[0];
  const int*   adj= (const int*)d_in[1];
  const float* W  = (const float*)d_in[2];
  const float* Wb = (const float*)d_in[3];
  const float* Aw = (const float*)d_in[4];
  const float* Ab = (const float*)d_in[5];
  float* out = (float*)d_out;
  char* ws = (char*)d_ws;
  unsigned char* V8 = (unsigned char*)ws;                 // 3,538,944
  float* e_src = (float*)(ws + 3538944);                  // 98,304
  float* T     = (float*)(ws + 3637248);                  // 1,024
  float* Acat  = (float*)(ws + 3638272);                  // 3,072 (asv|adv|Wbc)
  unsigned short* wsw = (unsigned short*)(ws + 3641344);  // 131,072
  unsigned* bm = (unsigned*)(ws + 6918144);               // 4,718,592 (adj bitmask)
  unsigned short* out2b = (unsigned short*)(ws + 44666880); // nks x 4 x 1,769,472 (panels)
  float* out2e = (float*)(ws + 87134208);                   // nks x 1,572,864

  const size_t slabB = (size_t)4 * NN * 144 * 2;   // 7,077,888 per ks
  const size_t slabE = (size_t)NN * 64 * 4;        // 1,572,864 per ks
  int nks = 2;
  if (ws_size >= 44666880 + 4 * slabB + 4 * slabE)  nks = 4;  // 768 blocks = 3/CU x 256 CU

  hipLaunchKernelGGL(p0s, dim3(9), dim3(256), 0, stream,
                     W, Aw, Wb, wsw, Acat, T);
  hipLaunchKernelGGL(k1m, dim3(4800), dim3(256), 0, stream,
                     x, wsw, Acat, Ab, adj, bm, V8, e_src, T);
  hipLaunchKernelGGL(k2_gemm, dim3(192 * nks), dim3(256), 0, stream, bm, V8, out2b, out2e, nks);
  hipLaunchKernelGGL(k3_final, dim3(NN), dim3(256), 0, stream, out2b, out2e, e_src, T, out, nks);
}

// Round 10
// 263.649 us; speedup vs baseline: 1.0445x; 1.0445x over previous
//
#include <hip/hip_runtime.h>
#include <stdint.h>

#define NN 6144        // nodes
#define NC 576         // padded V columns (517 used)

typedef float f32x4 __attribute__((ext_vector_type(4)));
typedef __bf16 bf16x8v __attribute__((ext_vector_type(8)));
typedef int i32x8 __attribute__((ext_vector_type(8)));

__device__ __forceinline__ unsigned short f2bf(float f) {
  unsigned u = __float_as_uint(f);
  u += 0x7FFFu + ((u >> 16) & 1u);   // RNE
  return (unsigned short)(u >> 16);
}

__device__ __forceinline__ float bf2f(unsigned short s) {
  unsigned u = (unsigned)s << 16;
  return __uint_as_float(u);
}

// f32 -> OCP e4m3fn, RNE, clamp to +-448
__device__ __forceinline__ unsigned char f2e4m3(float f) {
  unsigned u = __float_as_uint(f);
  unsigned sgn = (u >> 24) & 0x80u;
  unsigned au = u & 0x7FFFFFFFu;
  if (au >= 0x43E00000u) return (unsigned char)(sgn | 0x7E);
  if (au < 0x3C800000u) {
    int q = (int)rintf(__uint_as_float(au) * 512.0f);
    return (unsigned char)(sgn | (q >= 8 ? 0x08 : q));
  }
  unsigned r = au + 0x7FFFFu + ((au >> 20) & 1u);
  int e = (int)(r >> 23) - 127;
  unsigned m = (r >> 20) & 7u;
  return (unsigned char)(sgn | ((unsigned)(e + 7) << 3) | m);
}

__device__ __forceinline__ unsigned short pack2(float a, float b) {
  return (unsigned short)f2e4m3(a) | ((unsigned short)f2e4m3(b) << 8);
}

__device__ __forceinline__ void async_load16(const void* g, void* l) {
  __builtin_amdgcn_global_load_lds(
      (__attribute__((address_space(1))) void*)(uintptr_t)g,
      (__attribute__((address_space(3))) void*)(uint32_t)(uintptr_t)l,
      16, 0, 0);
}

// ---------------- p0s: tiny prep (wsw + Acat + T only; x-conversion fused into k1m) ----
__global__ __launch_bounds__(256) void p0s(
    const float* __restrict__ W,
    const float* __restrict__ Aw, const float* __restrict__ Wb,
    unsigned short* __restrict__ wsw, float* __restrict__ Acat,
    float* __restrict__ T)
{
  const int bid = blockIdx.x, t = threadIdx.x;
  if (bid < 8) {           // wsw: 8192 entries (16 col-tiles x 8 kc x 64 lanes)
#pragma unroll
    for (int i = 0; i < 4; ++i) {
      const int e = bid * 256 + t + i * 2048;
      const int l = e & 63, kc = (e >> 6) & 7, ct = e >> 9;
      const int c = ct * 16 + (l & 15);
      const int h = c >> 6, d0 = c & 63;
      const int ks = kc * 32 + (l >> 4) * 8;
      const float* src = W + h * 16384 + ks * 64 + d0;
      unsigned uu[4];
#pragma unroll
      for (int j = 0; j < 4; ++j)
        uu[j] = (unsigned)f2bf(src[(2*j) * 64]) | ((unsigned)f2bf(src[(2*j+1) * 64]) << 16);
      *(uint4*)(wsw + (size_t)e * 8) = (uint4){uu[0], uu[1], uu[2], uu[3]};
    }
    return;
  }
  // bid == 8: Acat[asv|adv|Wbc], T zero
  T[t] = 0.f;
  const int h = t >> 6, d = t & 63;
  Acat[t]       = Aw[h * 128 + d];
  Acat[256 + t] = Aw[h * 128 + 64 + d];
  Acat[512 + t] = Wb[t];
}

// ---------------- k1m: feature MFMA w/ fused x->bf16 LDS staging (blocks 0..191)
//                  + adj->bitmask pack, coalesced via LDS repack (192..4799) ----
__global__ __launch_bounds__(256) void k1m(
    const float* __restrict__ x, const unsigned short* __restrict__ wsw,
    const float* __restrict__ Acat, const float* __restrict__ Ab,
    const int* __restrict__ adj, unsigned* __restrict__ bm,
    unsigned char* __restrict__ V8, float* __restrict__ e_src, float* __restrict__ T)
{
  // lsh: pack-branch = nibble array (8KB); MFMA-branch = lx (16KB) then lv (4x4KB)
  __shared__ unsigned char lsh[16384];
  __shared__ float lt[256];
  const int t = threadIdx.x;

  if (blockIdx.x >= 192) {   // ---- pack: adj int32 -> 1-bit mask, coalesced ----
    const int pb = blockIdx.x - 192;            // 0..4607; block covers 8192 ints
    const int4* src = (const int4*)adj + (size_t)pb * 2048;
    unsigned char* ln = lsh;                    // 2048 nibble-bytes
#pragma unroll
    for (int i = 0; i < 8; ++i) {               // lane-contiguous 16B loads (1KB/instr)
      int4 q = src[t + i * 256];
      unsigned nib = (unsigned)q.x | ((unsigned)q.y << 1) |
                     ((unsigned)q.z << 2) | ((unsigned)q.w << 3);
      ln[t + i * 256] = (unsigned char)nib;
    }
    __syncthreads();
    const uint2 b2 = *(const uint2*)(ln + t * 8);   // 8 nibbles for word t
    unsigned pl = (b2.x | (b2.x >> 4)) & 0x00FF00FFu; pl = (pl | (pl >> 8)) & 0xFFFFu;
    unsigned ph = (b2.y | (b2.y >> 4)) & 0x00FF00FFu; ph = (ph | (ph >> 8)) & 0xFFFFu;
    bm[pb * 256 + t] = pl | (ph << 16);
    return;
  }

  // ---- k1-part: block covers nodes 32b..32b+31 (waves 0,1: tile0; 2,3: tile1) ----
  const int w = t >> 6, l = t & 63;
  const int v = blockIdx.x * 4 + w;
  const int mt = v >> 1, nh = v & 1;
  const int i0 = mt * 16, c0 = nh * 128;
  const int lm = l & 15, lk = l >> 4;

  // stage x -> lx in the R10 fragment layout
  {
    unsigned short* lx = (unsigned short*)lsh;
    const float* xb = x + (size_t)(blockIdx.x * 32) * 256;
#pragma unroll
    for (int j = 0; j < 4; ++j) {
      const int e = t + j * 256;
      const int tile = e >> 9, e9 = e & 511;
      const int el = e9 & 63, kc = e9 >> 6;
      const int node = tile * 16 + (el & 15);
      const int ks = kc * 32 + (el >> 4) * 8;
      const float4* xp = (const float4*)(xb + (size_t)node * 256 + ks);
      float4 v0 = xp[0], v1 = xp[1];
      uint4 o;
      o.x = (unsigned)f2bf(v0.x) | ((unsigned)f2bf(v0.y) << 16);
      o.y = (unsigned)f2bf(v0.z) | ((unsigned)f2bf(v0.w) << 16);
      o.z = (unsigned)f2bf(v1.x) | ((unsigned)f2bf(v1.y) << 16);
      o.w = (unsigned)f2bf(v1.z) | ((unsigned)f2bf(v1.w) << 16);
      *(uint4*)(lx + (size_t)e * 8) = o;
    }
  }
  lt[t] = 0.f;
  __syncthreads();

  f32x4 acc[8];
#pragma unroll
  for (int nt = 0; nt < 8; ++nt) acc[nt] = (f32x4){0.f, 0.f, 0.f, 0.f};

  const unsigned short* ap = (const unsigned short*)lsh + (((size_t)(w >> 1)) * 512 + l) * 8;
  const unsigned short* bp = wsw + ((size_t)nh * 4096 + l) * 8;

#pragma unroll
  for (int kc = 0; kc < 8; ++kc) {
    bf16x8v a = *(const bf16x8v*)(ap + (size_t)kc * 512);
#pragma unroll
    for (int nt = 0; nt < 8; ++nt) {
      bf16x8v b = *(const bf16x8v*)(bp + ((size_t)nt * 512 + kc * 64) * 8);
      acc[nt] = __builtin_amdgcn_mfma_f32_16x16x32_bf16(a, b, acc[nt], 0, 0, 0);
    }
  }

  float asv[8], adv[8];
#pragma unroll
  for (int nt = 0; nt < 8; ++nt) {
    const int cc = c0 + nt * 16 + lm;
    const float wb = Acat[512 + cc];
#pragma unroll
    for (int rr = 0; rr < 4; ++rr) acc[nt][rr] += wb;
    asv[nt] = Acat[cc];
    adv[nt] = Acat[256 + cc];
  }

#pragma unroll
  for (int nt = 0; nt < 8; ++nt)
    atomicAdd(&lt[c0 + nt * 16 + lm], acc[nt][0] + acc[nt][1] + acc[nt][2] + acc[nt][3]);

  float ss[2][4], sd[2][4];
#pragma unroll
  for (int hl = 0; hl < 2; ++hl)
#pragma unroll
    for (int rr = 0; rr < 4; ++rr) {
      float s1 = 0.f, s2 = 0.f;
#pragma unroll
      for (int j = 0; j < 4; ++j) {
        s1 += acc[hl * 4 + j][rr] * asv[hl * 4 + j];
        s2 += acc[hl * 4 + j][rr] * adv[hl * 4 + j];
      }
      ss[hl][rr] = s1; sd[hl][rr] = s2;
    }
#pragma unroll
  for (int off = 1; off < 16; off <<= 1)
#pragma unroll
    for (int hl = 0; hl < 2; ++hl)
#pragma unroll
      for (int rr = 0; rr < 4; ++rr) {
        ss[hl][rr] += __shfl_xor(ss[hl][rr], off);
        sd[hl][rr] += __shfl_xor(sd[hl][rr], off);
      }

  float ed[2][4];
#pragma unroll
  for (int hl = 0; hl < 2; ++hl)
#pragma unroll
    for (int rr = 0; rr < 4; ++rr) ed[hl][rr] = expf(sd[hl][rr]);

  if (lm == 0) {
#pragma unroll
    for (int hl = 0; hl < 2; ++hl) {
      const int hh = nh * 2 + hl;
      const float ab = Ab[hh];
#pragma unroll
      for (int rr = 0; rr < 4; ++rr)
        e_src[(size_t)hh * NN + i0 + lk * 4 + rr] = expf(ss[hl][rr] + ab);
    }
  }

  // all waves are done reading lx; lsh becomes lv from here
  __syncthreads();

  unsigned char* mylv = lsh + w * 4096;
#pragma unroll
  for (int nt = 0; nt < 8; ++nt) {
    const int hl = nt >> 2;
    const int d = (nt & 3) * 16 + lm;
    const int lcE = hl * 128 + d;
    const int lcP = lcE + 64;
    *(unsigned short*)(mylv + lcE * 16 + lk * 4)     = pack2(ed[hl][0] * acc[nt][0], ed[hl][1] * acc[nt][1]);
    *(unsigned short*)(mylv + lcE * 16 + lk * 4 + 2) = pack2(ed[hl][2] * acc[nt][2], ed[hl][3] * acc[nt][3]);
    *(unsigned short*)(mylv + lcP * 16 + lk * 4)     = pack2(acc[nt][0], acc[nt][1]);
    *(unsigned short*)(mylv + lcP * 16 + lk * 4 + 2) = pack2(acc[nt][2], acc[nt][3]);
  }
#pragma unroll
  for (int j = 0; j < 4; ++j) {
    const int lc = j * 64 + l;
    uint4 val = *(const uint4*)(mylv + lc * 16);
    *(uint4*)(V8 + (size_t)(nh * 256 + lc) * NN + i0) = val;
  }
  if (lm == 0) {
#pragma unroll
    for (int hl = 0; hl < 2; ++hl) {
      const int hh = nh * 2 + hl;
      unsigned char* pq = V8 + (size_t)(512 + hh) * NN + i0 + lk * 4;
      *(unsigned short*)pq       = pack2(ed[hl][0], ed[hl][1]);
      *(unsigned short*)(pq + 2) = pack2(ed[hl][2], ed[hl][3]);
    }
    if (nh == 0)
      *(unsigned*)(V8 + (size_t)516 * NN + i0 + lk * 4) = 0x38383838u;
  }

  __syncthreads();
  atomicAdd(&T[t], lt[t]);
}

// ---------------- k2 v16: R7 2-phase dbuf structure + MX-scaled MFMA
// (mfma_scale_f32_16x16x128_f8f6f4, unit scales e8m0=127). One K=128 MFMA
// replaces four 16x16x32s at 2.27x rate -> MFMA floor 21 -> 10.5 us.
// Same LDS bytes/reads as R7; lane k-order consistent on A (bitmask-built)
// and B (slots lk*2, lk*2+1 after XOR swizzle). A bytes 0x08 = 2^-6 e4m3;
// epilogue x64 undoes (exact).
__global__ __launch_bounds__(256, 3) void k2_gemm(
    const unsigned* __restrict__ bm, const unsigned char* __restrict__ V8,
    unsigned short* __restrict__ out2b, float* __restrict__ out2e, int nks)
{
  __shared__ unsigned char lB[2][144 * 128];
  const int t   = threadIdx.x;
  const int ks  = blockIdx.x / 192;
  const int r   = blockIdx.x - ks * 192;
  const int cb  = r & 3;
  const int rb  = r >> 2;                 // 0..47
  const int krange = NN / nks;
  const int i0 = rb * 128, n0 = cb * 144, k0 = ks * krange;
  const int w = t >> 6, l = t & 63;
  const int lm = l & 15, lk = l >> 4;

  f32x4 acc[2][9];
#pragma unroll
  for (int mt = 0; mt < 2; ++mt)
#pragma unroll
    for (int nt = 0; nt < 9; ++nt) acc[mt][nt] = (f32x4){0.f, 0.f, 0.f, 0.f};

  int scol[5], sgr[5];
#pragma unroll
  for (int u = 0; u < 5; ++u) {
    const int gi = u * 256 + t;
    scol[u] = gi >> 3;
    sgr[u]  = (gi & 7) ^ (scol[u] & 7);
  }
  const int dbase4 = (1024 + (t & ~63)) * 16;

  // per-row bitmask: row stride NN/32 = 192 u32; thread covers k-window lk*32..+31
  const unsigned* gA0 = bm + (size_t)(i0 + w * 32 + lm) * (NN / 32) + (k0 >> 5) + lk;
  const unsigned char* gBb = V8 + (size_t)n0 * NN + k0;

  const int iters = krange / 128;

#define K2_STAGE(BUF, IT)                                                        \
  do {                                                                           \
    const unsigned char* gB = gBb + (IT) * 128;                                  \
    _Pragma("unroll")                                                            \
    for (int u = 0; u < 4; ++u)                                                  \
      async_load16(gB + (size_t)scol[u] * NN + sgr[u] * 16,                      \
                   (char*)lB[BUF] + (size_t)(u * 256 + (t & ~63)) * 16);         \
    if (t < 128)                                                                 \
      async_load16(gB + (size_t)scol[4] * NN + sgr[4] * 16,                      \
                   (char*)lB[BUF] + dbase4);                                     \
  } while (0)

  unsigned bits_c[2], bits_n[2];
  K2_STAGE(0, 0);
#pragma unroll
  for (int mt = 0; mt < 2; ++mt) bits_c[mt] = gA0[(size_t)mt * 16 * (NN / 32)];
  __syncthreads();

  int cur = 0;
  for (int it = 0; it < iters; ++it) {
    if (it + 1 < iters) {
      K2_STAGE(cur ^ 1, it + 1);
#pragma unroll
      for (int mt = 0; mt < 2; ++mt)
        bits_n[mt] = gA0[(size_t)mt * 16 * (NN / 32) + (it + 1) * 4];
    }

    // expand 32 bits -> 32 fp8 bytes (0x00 / 0x08) as the K=128 A fragment:
    // byte j of av[] = k_local lk*32 + j  (matches B slot order below)
    i32x8 av[2];
#pragma unroll
    for (int mt = 0; mt < 2; ++mt) {
#pragma unroll
      for (int i = 0; i < 8; ++i) {
        unsigned nib = (bits_c[mt] >> (4 * i)) & 0xFu;
        av[mt][i] = (int)(((nib * 0x00204081u) & 0x01010101u) << 3);
      }
    }

#pragma unroll
    for (int nt = 0; nt < 9; ++nt) {
      const int cc = nt * 16 + lm;
      const int p0 = (lk * 2) ^ (cc & 7);
      const int p1 = (lk * 2 + 1) ^ (cc & 7);
      int4 q0 = *(const int4*)(lB[cur] + cc * 128 + p0 * 16);
      int4 q1 = *(const int4*)(lB[cur] + cc * 128 + p1 * 16);
      i32x8 bv = {q0.x, q0.y, q0.z, q0.w, q1.x, q1.y, q1.z, q1.w};
#pragma unroll
      for (int mt = 0; mt < 2; ++mt) {
        acc[mt][nt] = __builtin_amdgcn_mfma_scale_f32_16x16x128_f8f6f4(
            av[mt], bv, acc[mt][nt], 0, 0, 0, 127, 0, 127);
      }
    }

    if (it + 1 < iters) {
#pragma unroll
      for (int mt = 0; mt < 2; ++mt) bits_c[mt] = bits_n[mt];
    }
    __syncthreads();   // drains vmcnt(0): next tile landed; lgkmcnt(0): buf reads done
    cur ^= 1;
  }
#undef K2_STAGE

  // epilogue: x64 undoes the 2^-6 A-scale; per-wave LDS transpose -> panel chunks
  unsigned short* lw = (unsigned short*)((char*)lB[0] + w * 4608);
  float* oe = out2e + (size_t)ks * ((size_t)NN * 64);
  unsigned short* pb = out2b + ((size_t)(ks * 4 + cb) * NN + i0 + w * 32) * 144;
#pragma unroll
  for (int mt = 0; mt < 2; ++mt) {
#pragma unroll
    for (int nt = 0; nt < 9; ++nt) {
      const int coll = nt * 16 + lm;
#pragma unroll
      for (int rr = 0; rr < 4; ++rr)
        lw[(lk * 4 + rr) * 144 + coll] = f2bf(acc[mt][nt][rr] * 64.0f);
      if (cb == 3 && nt >= 5) {
        const int row = i0 + w * 32 + mt * 16 + lk * 4;
#pragma unroll
        for (int rr = 0; rr < 4; ++rr)
          oe[(size_t)(row + rr) * 64 + (n0 + coll - 512)] = acc[mt][nt][rr] * 64.0f;
      }
    }
    const uint4* ls = (const uint4*)((char*)lB[0] + w * 4608);
    char* dst = (char*)(pb + (size_t)mt * 16 * 144);
    for (int s = l; s < 288; s += 64)
      *(uint4*)(dst + s * 16) = ls[s];
  }
}

// ---------------- k3: combine across nks K-partials (R18-verified) ----------------
__global__ __launch_bounds__(256) void k3_final(
    const unsigned short* __restrict__ out2b, const float* __restrict__ out2e,
    const float* __restrict__ e_src, const float* __restrict__ T,
    float* __restrict__ out, int nks)
{
  const int n = blockIdx.x, c = threadIdx.x;
  const int h = c >> 6, d = c & 63;
  const int cS = h * 128 + d, cP = cS + 64;
  const int cbS = cS / 144, ofS = cS % 144;
  const int cbP = cP / 144, ofP = cP % 144;
  float Se = 0.f, Sp = 0.f, E = 0.f, dg = 0.f;
  for (int s = 0; s < nks; ++s) {
    const unsigned short* base = out2b + (size_t)s * 4 * NN * 144;
    Se += bf2f(base[((size_t)cbS * NN + n) * 144 + ofS]);
    Sp += bf2f(base[((size_t)cbP * NN + n) * 144 + ofP]);
    const float* re = out2e + (size_t)s * NN * 64 + (size_t)n * 64;
    E  += re[h];
    dg += re[4];
  }
  float e = e_src[h * NN + n];
  float D = e * E + ((float)NN - dg);
  out[(size_t)n * 256 + c] = (e * Se + (T[c] - Sp)) / D;
}

extern "C" void kernel_launch(void* const* d_in, const int* in_sizes, int n_in,
                              void* d_out, int out_size, void* d_ws, size_t ws_size,
                              hipStream_t stream) {
  const float* x  = (const float*)d_in[0];
  const int*   adj= (const int*)d_in[1];
  const float* W  = (const float*)d_in[2];
  const float* Wb = (const float*)d_in[3];
  const float* Aw = (const float*)d_in[4];
  const float* Ab = (const float*)d_in[5];
  float* out = (float*)d_out;
  char* ws = (char*)d_ws;
  unsigned char* V8 = (unsigned char*)ws;                 // 3,538,944
  float* e_src = (float*)(ws + 3538944);                  // 98,304
  float* T     = (float*)(ws + 3637248);                  // 1,024
  float* Acat  = (float*)(ws + 3638272);                  // 3,072 (asv|adv|Wbc)
  unsigned short* wsw = (unsigned short*)(ws + 3641344);  // 131,072
  unsigned* bm = (unsigned*)(ws + 6918144);               // 4,718,592 (adj bitmask)
  unsigned short* out2b = (unsigned short*)(ws + 44666880); // nks x 4 x 1,769,472 (panels)
  float* out2e = (float*)(ws + 87134208);                   // nks x 1,572,864

  const size_t slabB = (size_t)4 * NN * 144 * 2;   // 7,077,888 per ks
  const size_t slabE = (size_t)NN * 64 * 4;        // 1,572,864 per ks
  int nks = 2;
  if (ws_size >= 44666880 + 4 * slabB + 4 * slabE)  nks = 4;  // 768 blocks = 3/CU x 256 CU

  hipLaunchKernelGGL(p0s, dim3(9), dim3(256), 0, stream,
                     W, Aw, Wb, wsw, Acat, T);
  hipLaunchKernelGGL(k1m, dim3(4800), dim3(256), 0, stream,
                     x, wsw, Acat, Ab, adj, bm, V8, e_src, T);
  hipLaunchKernelGGL(k2_gemm, dim3(192 * nks), dim3(256), 0, stream, bm, V8, out2b, out2e, nks);
  hipLaunchKernelGGL(k3_final, dim3(NN), dim3(256), 0, stream, out2b, out2e, e_src, T, out, nks);
}

// Round 11
// 261.729 us; speedup vs baseline: 1.0521x; 1.0073x over previous
//
#include <hip/hip_runtime.h>
#include <stdint.h>

#define NN 6144        // nodes
#define NC 576         // padded V columns (517 used)

typedef float f32x4 __attribute__((ext_vector_type(4)));
typedef __bf16 bf16x8v __attribute__((ext_vector_type(8)));
typedef int i32x8 __attribute__((ext_vector_type(8)));

__device__ __forceinline__ unsigned short f2bf(float f) {
  unsigned u = __float_as_uint(f);
  u += 0x7FFFu + ((u >> 16) & 1u);   // RNE
  return (unsigned short)(u >> 16);
}

__device__ __forceinline__ float bf2f(unsigned short s) {
  unsigned u = (unsigned)s << 16;
  return __uint_as_float(u);
}

// f32 -> OCP e4m3fn, RNE, clamp to +-448
__device__ __forceinline__ unsigned char f2e4m3(float f) {
  unsigned u = __float_as_uint(f);
  unsigned sgn = (u >> 24) & 0x80u;
  unsigned au = u & 0x7FFFFFFFu;
  if (au >= 0x43E00000u) return (unsigned char)(sgn | 0x7E);
  if (au < 0x3C800000u) {
    int q = (int)rintf(__uint_as_float(au) * 512.0f);
    return (unsigned char)(sgn | (q >= 8 ? 0x08 : q));
  }
  unsigned r = au + 0x7FFFFu + ((au >> 20) & 1u);
  int e = (int)(r >> 23) - 127;
  unsigned m = (r >> 20) & 7u;
  return (unsigned char)(sgn | ((unsigned)(e + 7) << 3) | m);
}

__device__ __forceinline__ unsigned short pack2(float a, float b) {
  return (unsigned short)f2e4m3(a) | ((unsigned short)f2e4m3(b) << 8);
}

__device__ __forceinline__ void async_load16(const void* g, void* l) {
  __builtin_amdgcn_global_load_lds(
      (__attribute__((address_space(1))) void*)(uintptr_t)g,
      (__attribute__((address_space(3))) void*)(uint32_t)(uintptr_t)l,
      16, 0, 0);
}

// ---------------- p0s: tiny prep (wsw + Acat + T only; x-conversion fused into k1m) ----
__global__ __launch_bounds__(256) void p0s(
    const float* __restrict__ W,
    const float* __restrict__ Aw, const float* __restrict__ Wb,
    unsigned short* __restrict__ wsw, float* __restrict__ Acat,
    float* __restrict__ T)
{
  const int bid = blockIdx.x, t = threadIdx.x;
  if (bid < 8) {           // wsw: 8192 entries (16 col-tiles x 8 kc x 64 lanes)
#pragma unroll
    for (int i = 0; i < 4; ++i) {
      const int e = bid * 256 + t + i * 2048;
      const int l = e & 63, kc = (e >> 6) & 7, ct = e >> 9;
      const int c = ct * 16 + (l & 15);
      const int h = c >> 6, d0 = c & 63;
      const int ks = kc * 32 + (l >> 4) * 8;
      const float* src = W + h * 16384 + ks * 64 + d0;
      unsigned uu[4];
#pragma unroll
      for (int j = 0; j < 4; ++j)
        uu[j] = (unsigned)f2bf(src[(2*j) * 64]) | ((unsigned)f2bf(src[(2*j+1) * 64]) << 16);
      *(uint4*)(wsw + (size_t)e * 8) = (uint4){uu[0], uu[1], uu[2], uu[3]};
    }
    return;
  }
  // bid == 8: Acat[asv|adv|Wbc], T zero
  T[t] = 0.f;
  const int h = t >> 6, d = t & 63;
  Acat[t]       = Aw[h * 128 + d];
  Acat[256 + t] = Aw[h * 128 + 64 + d];
  Acat[512 + t] = Wb[t];
}

// ---------------- k1m: feature MFMA w/ fused x->bf16 LDS staging (blocks 0..191)
//                  + adj->bitmask pack, coalesced via LDS repack (192..4799) ----
__global__ __launch_bounds__(256) void k1m(
    const float* __restrict__ x, const unsigned short* __restrict__ wsw,
    const float* __restrict__ Acat, const float* __restrict__ Ab,
    const int* __restrict__ adj, unsigned* __restrict__ bm,
    unsigned char* __restrict__ V8, float* __restrict__ e_src, float* __restrict__ T)
{
  // lsh: pack-branch = nibble array (8KB); MFMA-branch = lx (16KB) then lv (4x4KB)
  __shared__ unsigned char lsh[16384];
  __shared__ float lt[256];
  const int t = threadIdx.x;

  if (blockIdx.x >= 192) {   // ---- pack: adj int32 -> 1-bit mask, coalesced ----
    const int pb = blockIdx.x - 192;            // 0..4607; block covers 8192 ints
    const int4* src = (const int4*)adj + (size_t)pb * 2048;
    unsigned char* ln = lsh;                    // 2048 nibble-bytes
#pragma unroll
    for (int i = 0; i < 8; ++i) {               // lane-contiguous 16B loads (1KB/instr)
      int4 q = src[t + i * 256];
      unsigned nib = (unsigned)q.x | ((unsigned)q.y << 1) |
                     ((unsigned)q.z << 2) | ((unsigned)q.w << 3);
      ln[t + i * 256] = (unsigned char)nib;
    }
    __syncthreads();
    const uint2 b2 = *(const uint2*)(ln + t * 8);   // 8 nibbles for word t
    unsigned pl = (b2.x | (b2.x >> 4)) & 0x00FF00FFu; pl = (pl | (pl >> 8)) & 0xFFFFu;
    unsigned ph = (b2.y | (b2.y >> 4)) & 0x00FF00FFu; ph = (ph | (ph >> 8)) & 0xFFFFu;
    bm[pb * 256 + t] = pl | (ph << 16);
    return;
  }

  // ---- k1-part: block covers nodes 32b..32b+31 (waves 0,1: tile0; 2,3: tile1) ----
  const int w = t >> 6, l = t & 63;
  const int v = blockIdx.x * 4 + w;
  const int mt = v >> 1, nh = v & 1;
  const int i0 = mt * 16, c0 = nh * 128;
  const int lm = l & 15, lk = l >> 4;

  // stage x -> lx in the R10 fragment layout
  {
    unsigned short* lx = (unsigned short*)lsh;
    const float* xb = x + (size_t)(blockIdx.x * 32) * 256;
#pragma unroll
    for (int j = 0; j < 4; ++j) {
      const int e = t + j * 256;
      const int tile = e >> 9, e9 = e & 511;
      const int el = e9 & 63, kc = e9 >> 6;
      const int node = tile * 16 + (el & 15);
      const int ks = kc * 32 + (el >> 4) * 8;
      const float4* xp = (const float4*)(xb + (size_t)node * 256 + ks);
      float4 v0 = xp[0], v1 = xp[1];
      uint4 o;
      o.x = (unsigned)f2bf(v0.x) | ((unsigned)f2bf(v0.y) << 16);
      o.y = (unsigned)f2bf(v0.z) | ((unsigned)f2bf(v0.w) << 16);
      o.z = (unsigned)f2bf(v1.x) | ((unsigned)f2bf(v1.y) << 16);
      o.w = (unsigned)f2bf(v1.z) | ((unsigned)f2bf(v1.w) << 16);
      *(uint4*)(lx + (size_t)e * 8) = o;
    }
  }
  lt[t] = 0.f;
  __syncthreads();

  f32x4 acc[8];
#pragma unroll
  for (int nt = 0; nt < 8; ++nt) acc[nt] = (f32x4){0.f, 0.f, 0.f, 0.f};

  const unsigned short* ap = (const unsigned short*)lsh + (((size_t)(w >> 1)) * 512 + l) * 8;
  const unsigned short* bp = wsw + ((size_t)nh * 4096 + l) * 8;

#pragma unroll
  for (int kc = 0; kc < 8; ++kc) {
    bf16x8v a = *(const bf16x8v*)(ap + (size_t)kc * 512);
#pragma unroll
    for (int nt = 0; nt < 8; ++nt) {
      bf16x8v b = *(const bf16x8v*)(bp + ((size_t)nt * 512 + kc * 64) * 8);
      acc[nt] = __builtin_amdgcn_mfma_f32_16x16x32_bf16(a, b, acc[nt], 0, 0, 0);
    }
  }

  float asv[8], adv[8];
#pragma unroll
  for (int nt = 0; nt < 8; ++nt) {
    const int cc = c0 + nt * 16 + lm;
    const float wb = Acat[512 + cc];
#pragma unroll
    for (int rr = 0; rr < 4; ++rr) acc[nt][rr] += wb;
    asv[nt] = Acat[cc];
    adv[nt] = Acat[256 + cc];
  }

#pragma unroll
  for (int nt = 0; nt < 8; ++nt)
    atomicAdd(&lt[c0 + nt * 16 + lm], acc[nt][0] + acc[nt][1] + acc[nt][2] + acc[nt][3]);

  float ss[2][4], sd[2][4];
#pragma unroll
  for (int hl = 0; hl < 2; ++hl)
#pragma unroll
    for (int rr = 0; rr < 4; ++rr) {
      float s1 = 0.f, s2 = 0.f;
#pragma unroll
      for (int j = 0; j < 4; ++j) {
        s1 += acc[hl * 4 + j][rr] * asv[hl * 4 + j];
        s2 += acc[hl * 4 + j][rr] * adv[hl * 4 + j];
      }
      ss[hl][rr] = s1; sd[hl][rr] = s2;
    }
#pragma unroll
  for (int off = 1; off < 16; off <<= 1)
#pragma unroll
    for (int hl = 0; hl < 2; ++hl)
#pragma unroll
      for (int rr = 0; rr < 4; ++rr) {
        ss[hl][rr] += __shfl_xor(ss[hl][rr], off);
        sd[hl][rr] += __shfl_xor(sd[hl][rr], off);
      }

  float ed[2][4];
#pragma unroll
  for (int hl = 0; hl < 2; ++hl)
#pragma unroll
    for (int rr = 0; rr < 4; ++rr) ed[hl][rr] = expf(sd[hl][rr]);

  if (lm == 0) {
#pragma unroll
    for (int hl = 0; hl < 2; ++hl) {
      const int hh = nh * 2 + hl;
      const float ab = Ab[hh];
#pragma unroll
      for (int rr = 0; rr < 4; ++rr)
        e_src[(size_t)hh * NN + i0 + lk * 4 + rr] = expf(ss[hl][rr] + ab);
    }
  }

  // all waves are done reading lx; lsh becomes lv from here
  __syncthreads();

  unsigned char* mylv = lsh + w * 4096;
#pragma unroll
  for (int nt = 0; nt < 8; ++nt) {
    const int hl = nt >> 2;
    const int d = (nt & 3) * 16 + lm;
    const int lcE = hl * 128 + d;
    const int lcP = lcE + 64;
    *(unsigned short*)(mylv + lcE * 16 + lk * 4)     = pack2(ed[hl][0] * acc[nt][0], ed[hl][1] * acc[nt][1]);
    *(unsigned short*)(mylv + lcE * 16 + lk * 4 + 2) = pack2(ed[hl][2] * acc[nt][2], ed[hl][3] * acc[nt][3]);
    *(unsigned short*)(mylv + lcP * 16 + lk * 4)     = pack2(acc[nt][0], acc[nt][1]);
    *(unsigned short*)(mylv + lcP * 16 + lk * 4 + 2) = pack2(acc[nt][2], acc[nt][3]);
  }
#pragma unroll
  for (int j = 0; j < 4; ++j) {
    const int lc = j * 64 + l;
    uint4 val = *(const uint4*)(mylv + lc * 16);
    *(uint4*)(V8 + (size_t)(nh * 256 + lc) * NN + i0) = val;
  }
  if (lm == 0) {
#pragma unroll
    for (int hl = 0; hl < 2; ++hl) {
      const int hh = nh * 2 + hl;
      unsigned char* pq = V8 + (size_t)(512 + hh) * NN + i0 + lk * 4;
      *(unsigned short*)pq       = pack2(ed[hl][0], ed[hl][1]);
      *(unsigned short*)(pq + 2) = pack2(ed[hl][2], ed[hl][3]);
    }
    if (nh == 0)
      *(unsigned*)(V8 + (size_t)516 * NN + i0 + lk * 4) = 0x38383838u;
  }

  __syncthreads();
  atomicAdd(&T[t], lt[t]);
}

// ---------------- k2 v17: v16 (MX-scaled MFMA, 2-phase dbuf) + K-PHASE STAGGER.
// Co-resident blocks start at different K-tiles (it0 = bid % iters) and walk
// circularly, so their vmcnt(0)-barrier drains decorrelate and one block's
// MFMA phase covers another's drain. Accumulation-order change only (f32,
// within tolerance). A bytes 0x08 = 2^-6 e4m3; epilogue x64 undoes (exact).
__global__ __launch_bounds__(256, 3) void k2_gemm(
    const unsigned* __restrict__ bm, const unsigned char* __restrict__ V8,
    unsigned short* __restrict__ out2b, float* __restrict__ out2e, int nks)
{
  __shared__ unsigned char lB[2][144 * 128];
  const int t   = threadIdx.x;
  const int ks  = blockIdx.x / 192;
  const int r   = blockIdx.x - ks * 192;
  const int cb  = r & 3;
  const int rb  = r >> 2;                 // 0..47
  const int krange = NN / nks;
  const int i0 = rb * 128, n0 = cb * 144, k0 = ks * krange;
  const int w = t >> 6, l = t & 63;
  const int lm = l & 15, lk = l >> 4;

  f32x4 acc[2][9];
#pragma unroll
  for (int mt = 0; mt < 2; ++mt)
#pragma unroll
    for (int nt = 0; nt < 9; ++nt) acc[mt][nt] = (f32x4){0.f, 0.f, 0.f, 0.f};

  int scol[5], sgr[5];
#pragma unroll
  for (int u = 0; u < 5; ++u) {
    const int gi = u * 256 + t;
    scol[u] = gi >> 3;
    sgr[u]  = (gi & 7) ^ (scol[u] & 7);
  }
  const int dbase4 = (1024 + (t & ~63)) * 16;

  // per-row bitmask: row stride NN/32 = 192 u32; thread covers k-window lk*32..+31
  const unsigned* gA0 = bm + (size_t)(i0 + w * 32 + lm) * (NN / 32) + (k0 >> 5) + lk;
  const unsigned char* gBb = V8 + (size_t)n0 * NN + k0;

  const int iters = krange / 128;
  const int it0 = (int)(blockIdx.x % (unsigned)iters);   // phase stagger

#define K2_STAGE(BUF, ITP)                                                       \
  do {                                                                           \
    const unsigned char* gB = gBb + (ITP) * 128;                                 \
    _Pragma("unroll")                                                            \
    for (int u = 0; u < 4; ++u)                                                  \
      async_load16(gB + (size_t)scol[u] * NN + sgr[u] * 16,                      \
                   (char*)lB[BUF] + (size_t)(u * 256 + (t & ~63)) * 16);         \
    if (t < 128)                                                                 \
      async_load16(gB + (size_t)scol[4] * NN + sgr[4] * 16,                      \
                   (char*)lB[BUF] + dbase4);                                     \
  } while (0)

  unsigned bits_c[2], bits_n[2];
  K2_STAGE(0, it0);
#pragma unroll
  for (int mt = 0; mt < 2; ++mt)
    bits_c[mt] = gA0[(size_t)mt * 16 * (NN / 32) + it0 * 4];
  __syncthreads();

  int cur = 0;
  int itp = it0;                       // current physical tile
  for (int it = 0; it < iters; ++it) {
    int itn = itp + 1; if (itn == iters) itn = 0;   // next physical tile
    if (it + 1 < iters) {
      K2_STAGE(cur ^ 1, itn);
#pragma unroll
      for (int mt = 0; mt < 2; ++mt)
        bits_n[mt] = gA0[(size_t)mt * 16 * (NN / 32) + itn * 4];
    }

    // expand 32 bits -> 32 fp8 bytes (0x00 / 0x08) as the K=128 A fragment
    i32x8 av[2];
#pragma unroll
    for (int mt = 0; mt < 2; ++mt) {
#pragma unroll
      for (int i = 0; i < 8; ++i) {
        unsigned nib = (bits_c[mt] >> (4 * i)) & 0xFu;
        av[mt][i] = (int)(((nib * 0x00204081u) & 0x01010101u) << 3);
      }
    }

#pragma unroll
    for (int nt = 0; nt < 9; ++nt) {
      const int cc = nt * 16 + lm;
      const int p0 = (lk * 2) ^ (cc & 7);
      const int p1 = (lk * 2 + 1) ^ (cc & 7);
      int4 q0 = *(const int4*)(lB[cur] + cc * 128 + p0 * 16);
      int4 q1 = *(const int4*)(lB[cur] + cc * 128 + p1 * 16);
      i32x8 bv = {q0.x, q0.y, q0.z, q0.w, q1.x, q1.y, q1.z, q1.w};
#pragma unroll
      for (int mt = 0; mt < 2; ++mt) {
        acc[mt][nt] = __builtin_amdgcn_mfma_scale_f32_16x16x128_f8f6f4(
            av[mt], bv, acc[mt][nt], 0, 0, 0, 127, 0, 127);
      }
    }

    if (it + 1 < iters) {
#pragma unroll
      for (int mt = 0; mt < 2; ++mt) bits_c[mt] = bits_n[mt];
    }
    __syncthreads();   // drains vmcnt(0): next tile landed; lgkmcnt(0): buf reads done
    cur ^= 1;
    itp = itn;
  }
#undef K2_STAGE

  // epilogue: x64 undoes the 2^-6 A-scale; per-wave LDS transpose -> panel chunks
  unsigned short* lw = (unsigned short*)((char*)lB[0] + w * 4608);
  float* oe = out2e + (size_t)ks * ((size_t)NN * 64);
  unsigned short* pb = out2b + ((size_t)(ks * 4 + cb) * NN + i0 + w * 32) * 144;
#pragma unroll
  for (int mt = 0; mt < 2; ++mt) {
#pragma unroll
    for (int nt = 0; nt < 9; ++nt) {
      const int coll = nt * 16 + lm;
#pragma unroll
      for (int rr = 0; rr < 4; ++rr)
        lw[(lk * 4 + rr) * 144 + coll] = f2bf(acc[mt][nt][rr] * 64.0f);
      if (cb == 3 && nt >= 5) {
        const int row = i0 + w * 32 + mt * 16 + lk * 4;
#pragma unroll
        for (int rr = 0; rr < 4; ++rr)
          oe[(size_t)(row + rr) * 64 + (n0 + coll - 512)] = acc[mt][nt][rr] * 64.0f;
      }
    }
    const uint4* ls = (const uint4*)((char*)lB[0] + w * 4608);
    char* dst = (char*)(pb + (size_t)mt * 16 * 144);
    for (int s = l; s < 288; s += 64)
      *(uint4*)(dst + s * 16) = ls[s];
  }
}

// ---------------- k3: combine across nks K-partials (R18-verified) ----------------
__global__ __launch_bounds__(256) void k3_final(
    const unsigned short* __restrict__ out2b, const float* __restrict__ out2e,
    const float* __restrict__ e_src, const float* __restrict__ T,
    float* __restrict__ out, int nks)
{
  const int n = blockIdx.x, c = threadIdx.x;
  const int h = c >> 6, d = c & 63;
  const int cS = h * 128 + d, cP = cS + 64;
  const int cbS = cS / 144, ofS = cS % 144;
  const int cbP = cP / 144, ofP = cP % 144;
  float Se = 0.f, Sp = 0.f, E = 0.f, dg = 0.f;
  for (int s = 0; s < nks; ++s) {
    const unsigned short* base = out2b + (size_t)s * 4 * NN * 144;
    Se += bf2f(base[((size_t)cbS * NN + n) * 144 + ofS]);
    Sp += bf2f(base[((size_t)cbP * NN + n) * 144 + ofP]);
    const float* re = out2e + (size_t)s * NN * 64 + (size_t)n * 64;
    E  += re[h];
    dg += re[4];
  }
  float e = e_src[h * NN + n];
  float D = e * E + ((float)NN - dg);
  out[(size_t)n * 256 + c] = (e * Se + (T[c] - Sp)) / D;
}

extern "C" void kernel_launch(void* const* d_in, const int* in_sizes, int n_in,
                              void* d_out, int out_size, void* d_ws, size_t ws_size,
                              hipStream_t stream) {
  const float* x  = (const float*)d_in[0];
  const int*   adj= (const int*)d_in[1];
  const float* W  = (const float*)d_in[2];
  const float* Wb = (const float*)d_in[3];
  const float* Aw = (const float*)d_in[4];
  const float* Ab = (const float*)d_in[5];
  float* out = (float*)d_out;
  char* ws = (char*)d_ws;
  unsigned char* V8 = (unsigned char*)ws;                 // 3,538,944
  float* e_src = (float*)(ws + 3538944);                  // 98,304
  float* T     = (float*)(ws + 3637248);                  // 1,024
  float* Acat  = (float*)(ws + 3638272);                  // 3,072 (asv|adv|Wbc)
  unsigned short* wsw = (unsigned short*)(ws + 3641344);  // 131,072
  unsigned* bm = (unsigned*)(ws + 6918144);               // 4,718,592 (adj bitmask)
  unsigned short* out2b = (unsigned short*)(ws + 44666880); // nks x 4 x 1,769,472 (panels)
  float* out2e = (float*)(ws + 87134208);                   // nks x 1,572,864

  const size_t slabB = (size_t)4 * NN * 144 * 2;   // 7,077,888 per ks
  const size_t slabE = (size_t)NN * 64 * 4;        // 1,572,864 per ks
  int nks = 2;
  if (ws_size >= 44666880 + 4 * slabB + 4 * slabE)  nks = 4;  // 768 blocks = 3/CU x 256 CU

  hipLaunchKernelGGL(p0s, dim3(9), dim3(256), 0, stream,
                     W, Aw, Wb, wsw, Acat, T);
  hipLaunchKernelGGL(k1m, dim3(4800), dim3(256), 0, stream,
                     x, wsw, Acat, Ab, adj, bm, V8, e_src, T);
  hipLaunchKernelGGL(k2_gemm, dim3(192 * nks), dim3(256), 0, stream, bm, V8, out2b, out2e, nks);
  hipLaunchKernelGGL(k3_final, dim3(NN), dim3(256), 0, stream, out2b, out2e, e_src, T, out, nks);
}

// Round 12
// 261.587 us; speedup vs baseline: 1.0527x; 1.0005x over previous
//
#include <hip/hip_runtime.h>
#include <stdint.h>

#define NN 6144        // nodes
#define NC 576         // padded V columns (517 used)

typedef float f32x4 __attribute__((ext_vector_type(4)));
typedef __bf16 bf16x8v __attribute__((ext_vector_type(8)));
typedef int i32x8 __attribute__((ext_vector_type(8)));

__device__ __forceinline__ unsigned short f2bf(float f) {
  unsigned u = __float_as_uint(f);
  u += 0x7FFFu + ((u >> 16) & 1u);   // RNE
  return (unsigned short)(u >> 16);
}

__device__ __forceinline__ float bf2f(unsigned short s) {
  unsigned u = (unsigned)s << 16;
  return __uint_as_float(u);
}

// f32 -> OCP e4m3fn, RNE, clamp to +-448
__device__ __forceinline__ unsigned char f2e4m3(float f) {
  unsigned u = __float_as_uint(f);
  unsigned sgn = (u >> 24) & 0x80u;
  unsigned au = u & 0x7FFFFFFFu;
  if (au >= 0x43E00000u) return (unsigned char)(sgn | 0x7E);
  if (au < 0x3C800000u) {
    int q = (int)rintf(__uint_as_float(au) * 512.0f);
    return (unsigned char)(sgn | (q >= 8 ? 0x08 : q));
  }
  unsigned r = au + 0x7FFFFu + ((au >> 20) & 1u);
  int e = (int)(r >> 23) - 127;
  unsigned m = (r >> 20) & 7u;
  return (unsigned char)(sgn | ((unsigned)(e + 7) << 3) | m);
}

__device__ __forceinline__ unsigned short pack2(float a, float b) {
  return (unsigned short)f2e4m3(a) | ((unsigned short)f2e4m3(b) << 8);
}

__device__ __forceinline__ void async_load16(const void* g, void* l) {
  __builtin_amdgcn_global_load_lds(
      (__attribute__((address_space(1))) void*)(uintptr_t)g,
      (__attribute__((address_space(3))) void*)(uint32_t)(uintptr_t)l,
      16, 0, 0);
}

// ---------------- p0s: tiny prep (wsw + Acat + T only; x-conversion fused into k1m) ----
__global__ __launch_bounds__(256) void p0s(
    const float* __restrict__ W,
    const float* __restrict__ Aw, const float* __restrict__ Wb,
    unsigned short* __restrict__ wsw, float* __restrict__ Acat,
    float* __restrict__ T)
{
  const int bid = blockIdx.x, t = threadIdx.x;
  if (bid < 8) {           // wsw: 8192 entries (16 col-tiles x 8 kc x 64 lanes)
#pragma unroll
    for (int i = 0; i < 4; ++i) {
      const int e = bid * 256 + t + i * 2048;
      const int l = e & 63, kc = (e >> 6) & 7, ct = e >> 9;
      const int c = ct * 16 + (l & 15);
      const int h = c >> 6, d0 = c & 63;
      const int ks = kc * 32 + (l >> 4) * 8;
      const float* src = W + h * 16384 + ks * 64 + d0;
      unsigned uu[4];
#pragma unroll
      for (int j = 0; j < 4; ++j)
        uu[j] = (unsigned)f2bf(src[(2*j) * 64]) | ((unsigned)f2bf(src[(2*j+1) * 64]) << 16);
      *(uint4*)(wsw + (size_t)e * 8) = (uint4){uu[0], uu[1], uu[2], uu[3]};
    }
    return;
  }
  // bid == 8: Acat[asv|adv|Wbc], T zero
  T[t] = 0.f;
  const int h = t >> 6, d = t & 63;
  Acat[t]       = Aw[h * 128 + d];
  Acat[256 + t] = Aw[h * 128 + 64 + d];
  Acat[512 + t] = Wb[t];
}

// ---------------- k1m: feature MFMA w/ fused x->bf16 LDS staging (blocks 0..191)
//                  + adj->bitmask pack, coalesced via LDS repack (192..4799) ----
__global__ __launch_bounds__(256) void k1m(
    const float* __restrict__ x, const unsigned short* __restrict__ wsw,
    const float* __restrict__ Acat, const float* __restrict__ Ab,
    const int* __restrict__ adj, unsigned* __restrict__ bm,
    unsigned char* __restrict__ V8, float* __restrict__ e_src, float* __restrict__ T)
{
  // lsh: pack-branch = nibble array (8KB); MFMA-branch = lx (16KB) then lv (4x4KB)
  __shared__ unsigned char lsh[16384];
  __shared__ float lt[256];
  const int t = threadIdx.x;

  if (blockIdx.x >= 192) {   // ---- pack: adj int32 -> 1-bit mask, coalesced ----
    const int pb = blockIdx.x - 192;            // 0..4607; block covers 8192 ints
    const int4* src = (const int4*)adj + (size_t)pb * 2048;
    unsigned char* ln = lsh;                    // 2048 nibble-bytes
#pragma unroll
    for (int i = 0; i < 8; ++i) {               // lane-contiguous 16B loads (1KB/instr)
      int4 q = src[t + i * 256];
      unsigned nib = (unsigned)q.x | ((unsigned)q.y << 1) |
                     ((unsigned)q.z << 2) | ((unsigned)q.w << 3);
      ln[t + i * 256] = (unsigned char)nib;
    }
    __syncthreads();
    const uint2 b2 = *(const uint2*)(ln + t * 8);   // 8 nibbles for word t
    unsigned pl = (b2.x | (b2.x >> 4)) & 0x00FF00FFu; pl = (pl | (pl >> 8)) & 0xFFFFu;
    unsigned ph = (b2.y | (b2.y >> 4)) & 0x00FF00FFu; ph = (ph | (ph >> 8)) & 0xFFFFu;
    bm[pb * 256 + t] = pl | (ph << 16);
    return;
  }

  // ---- k1-part: block covers nodes 32b..32b+31 (waves 0,1: tile0; 2,3: tile1) ----
  const int w = t >> 6, l = t & 63;
  const int v = blockIdx.x * 4 + w;
  const int mt = v >> 1, nh = v & 1;
  const int i0 = mt * 16, c0 = nh * 128;
  const int lm = l & 15, lk = l >> 4;

  // stage x -> lx in the R10 fragment layout
  {
    unsigned short* lx = (unsigned short*)lsh;
    const float* xb = x + (size_t)(blockIdx.x * 32) * 256;
#pragma unroll
    for (int j = 0; j < 4; ++j) {
      const int e = t + j * 256;
      const int tile = e >> 9, e9 = e & 511;
      const int el = e9 & 63, kc = e9 >> 6;
      const int node = tile * 16 + (el & 15);
      const int ks = kc * 32 + (el >> 4) * 8;
      const float4* xp = (const float4*)(xb + (size_t)node * 256 + ks);
      float4 v0 = xp[0], v1 = xp[1];
      uint4 o;
      o.x = (unsigned)f2bf(v0.x) | ((unsigned)f2bf(v0.y) << 16);
      o.y = (unsigned)f2bf(v0.z) | ((unsigned)f2bf(v0.w) << 16);
      o.z = (unsigned)f2bf(v1.x) | ((unsigned)f2bf(v1.y) << 16);
      o.w = (unsigned)f2bf(v1.z) | ((unsigned)f2bf(v1.w) << 16);
      *(uint4*)(lx + (size_t)e * 8) = o;
    }
  }
  lt[t] = 0.f;
  __syncthreads();

  f32x4 acc[8];
#pragma unroll
  for (int nt = 0; nt < 8; ++nt) acc[nt] = (f32x4){0.f, 0.f, 0.f, 0.f};

  const unsigned short* ap = (const unsigned short*)lsh + (((size_t)(w >> 1)) * 512 + l) * 8;
  const unsigned short* bp = wsw + ((size_t)nh * 4096 + l) * 8;

#pragma unroll
  for (int kc = 0; kc < 8; ++kc) {
    bf16x8v a = *(const bf16x8v*)(ap + (size_t)kc * 512);
#pragma unroll
    for (int nt = 0; nt < 8; ++nt) {
      bf16x8v b = *(const bf16x8v*)(bp + ((size_t)nt * 512 + kc * 64) * 8);
      acc[nt] = __builtin_amdgcn_mfma_f32_16x16x32_bf16(a, b, acc[nt], 0, 0, 0);
    }
  }

  float asv[8], adv[8];
#pragma unroll
  for (int nt = 0; nt < 8; ++nt) {
    const int cc = c0 + nt * 16 + lm;
    const float wb = Acat[512 + cc];
#pragma unroll
    for (int rr = 0; rr < 4; ++rr) acc[nt][rr] += wb;
    asv[nt] = Acat[cc];
    adv[nt] = Acat[256 + cc];
  }

#pragma unroll
  for (int nt = 0; nt < 8; ++nt)
    atomicAdd(&lt[c0 + nt * 16 + lm], acc[nt][0] + acc[nt][1] + acc[nt][2] + acc[nt][3]);

  float ss[2][4], sd[2][4];
#pragma unroll
  for (int hl = 0; hl < 2; ++hl)
#pragma unroll
    for (int rr = 0; rr < 4; ++rr) {
      float s1 = 0.f, s2 = 0.f;
#pragma unroll
      for (int j = 0; j < 4; ++j) {
        s1 += acc[hl * 4 + j][rr] * asv[hl * 4 + j];
        s2 += acc[hl * 4 + j][rr] * adv[hl * 4 + j];
      }
      ss[hl][rr] = s1; sd[hl][rr] = s2;
    }
#pragma unroll
  for (int off = 1; off < 16; off <<= 1)
#pragma unroll
    for (int hl = 0; hl < 2; ++hl)
#pragma unroll
      for (int rr = 0; rr < 4; ++rr) {
        ss[hl][rr] += __shfl_xor(ss[hl][rr], off);
        sd[hl][rr] += __shfl_xor(sd[hl][rr], off);
      }

  float ed[2][4];
#pragma unroll
  for (int hl = 0; hl < 2; ++hl)
#pragma unroll
    for (int rr = 0; rr < 4; ++rr) ed[hl][rr] = expf(sd[hl][rr]);

  if (lm == 0) {
#pragma unroll
    for (int hl = 0; hl < 2; ++hl) {
      const int hh = nh * 2 + hl;
      const float ab = Ab[hh];
#pragma unroll
      for (int rr = 0; rr < 4; ++rr)
        e_src[(size_t)hh * NN + i0 + lk * 4 + rr] = expf(ss[hl][rr] + ab);
    }
  }

  // all waves are done reading lx; lsh becomes lv from here
  __syncthreads();

  unsigned char* mylv = lsh + w * 4096;
#pragma unroll
  for (int nt = 0; nt < 8; ++nt) {
    const int hl = nt >> 2;
    const int d = (nt & 3) * 16 + lm;
    const int lcE = hl * 128 + d;
    const int lcP = lcE + 64;
    *(unsigned short*)(mylv + lcE * 16 + lk * 4)     = pack2(ed[hl][0] * acc[nt][0], ed[hl][1] * acc[nt][1]);
    *(unsigned short*)(mylv + lcE * 16 + lk * 4 + 2) = pack2(ed[hl][2] * acc[nt][2], ed[hl][3] * acc[nt][3]);
    *(unsigned short*)(mylv + lcP * 16 + lk * 4)     = pack2(acc[nt][0], acc[nt][1]);
    *(unsigned short*)(mylv + lcP * 16 + lk * 4 + 2) = pack2(acc[nt][2], acc[nt][3]);
  }
#pragma unroll
  for (int j = 0; j < 4; ++j) {
    const int lc = j * 64 + l;
    uint4 val = *(const uint4*)(mylv + lc * 16);
    *(uint4*)(V8 + (size_t)(nh * 256 + lc) * NN + i0) = val;
  }
  if (lm == 0) {
#pragma unroll
    for (int hl = 0; hl < 2; ++hl) {
      const int hh = nh * 2 + hl;
      unsigned char* pq = V8 + (size_t)(512 + hh) * NN + i0 + lk * 4;
      *(unsigned short*)pq       = pack2(ed[hl][0], ed[hl][1]);
      *(unsigned short*)(pq + 2) = pack2(ed[hl][2], ed[hl][3]);
    }
    if (nh == 0)
      *(unsigned*)(V8 + (size_t)516 * NN + i0 + lk * 4) = 0x38383838u;
  }

  __syncthreads();
  atomicAdd(&T[t], lt[t]);
}

// ---------------- k2 v18: v17 (MX-scaled MFMA, 2-phase dbuf, K-stagger) at
// 4 blocks/CU (__launch_bounds__(256,4)). LDS 2x18.4KB x 4 = 147.5KB <= 160KB.
// TLP is the untested lever on the MX kernel: occupancy 29% -> ~39% to cover
// the barrier-latency gap. A bytes 0x08 = 2^-6 e4m3; epilogue x64 (exact).
__global__ __launch_bounds__(256, 4) void k2_gemm(
    const unsigned* __restrict__ bm, const unsigned char* __restrict__ V8,
    unsigned short* __restrict__ out2b, float* __restrict__ out2e, int nks)
{
  __shared__ unsigned char lB[2][144 * 128];
  const int t   = threadIdx.x;
  const int ks  = blockIdx.x / 192;
  const int r   = blockIdx.x - ks * 192;
  const int cb  = r & 3;
  const int rb  = r >> 2;                 // 0..47
  const int krange = NN / nks;
  const int i0 = rb * 128, n0 = cb * 144, k0 = ks * krange;
  const int w = t >> 6, l = t & 63;
  const int lm = l & 15, lk = l >> 4;

  f32x4 acc[2][9];
#pragma unroll
  for (int mt = 0; mt < 2; ++mt)
#pragma unroll
    for (int nt = 0; nt < 9; ++nt) acc[mt][nt] = (f32x4){0.f, 0.f, 0.f, 0.f};

  int scol[5], sgr[5];
#pragma unroll
  for (int u = 0; u < 5; ++u) {
    const int gi = u * 256 + t;
    scol[u] = gi >> 3;
    sgr[u]  = (gi & 7) ^ (scol[u] & 7);
  }
  const int dbase4 = (1024 + (t & ~63)) * 16;

  // per-row bitmask: row stride NN/32 = 192 u32; thread covers k-window lk*32..+31
  const unsigned* gA0 = bm + (size_t)(i0 + w * 32 + lm) * (NN / 32) + (k0 >> 5) + lk;
  const unsigned char* gBb = V8 + (size_t)n0 * NN + k0;

  const int iters = krange / 128;
  const int it0 = (int)(blockIdx.x % (unsigned)iters);   // phase stagger

#define K2_STAGE(BUF, ITP)                                                       \
  do {                                                                           \
    const unsigned char* gB = gBb + (ITP) * 128;                                 \
    _Pragma("unroll")                                                            \
    for (int u = 0; u < 4; ++u)                                                  \
      async_load16(gB + (size_t)scol[u] * NN + sgr[u] * 16,                      \
                   (char*)lB[BUF] + (size_t)(u * 256 + (t & ~63)) * 16);         \
    if (t < 128)                                                                 \
      async_load16(gB + (size_t)scol[4] * NN + sgr[4] * 16,                      \
                   (char*)lB[BUF] + dbase4);                                     \
  } while (0)

  unsigned bits_c[2], bits_n[2];
  K2_STAGE(0, it0);
#pragma unroll
  for (int mt = 0; mt < 2; ++mt)
    bits_c[mt] = gA0[(size_t)mt * 16 * (NN / 32) + it0 * 4];
  __syncthreads();

  int cur = 0;
  int itp = it0;                       // current physical tile
  for (int it = 0; it < iters; ++it) {
    int itn = itp + 1; if (itn == iters) itn = 0;   // next physical tile
    if (it + 1 < iters) {
      K2_STAGE(cur ^ 1, itn);
#pragma unroll
      for (int mt = 0; mt < 2; ++mt)
        bits_n[mt] = gA0[(size_t)mt * 16 * (NN / 32) + itn * 4];
    }

    // expand 32 bits -> 32 fp8 bytes (0x00 / 0x08) as the K=128 A fragment
    i32x8 av[2];
#pragma unroll
    for (int mt = 0; mt < 2; ++mt) {
#pragma unroll
      for (int i = 0; i < 8; ++i) {
        unsigned nib = (bits_c[mt] >> (4 * i)) & 0xFu;
        av[mt][i] = (int)(((nib * 0x00204081u) & 0x01010101u) << 3);
      }
    }

#pragma unroll
    for (int nt = 0; nt < 9; ++nt) {
      const int cc = nt * 16 + lm;
      const int p0 = (lk * 2) ^ (cc & 7);
      const int p1 = (lk * 2 + 1) ^ (cc & 7);
      int4 q0 = *(const int4*)(lB[cur] + cc * 128 + p0 * 16);
      int4 q1 = *(const int4*)(lB[cur] + cc * 128 + p1 * 16);
      i32x8 bv = {q0.x, q0.y, q0.z, q0.w, q1.x, q1.y, q1.z, q1.w};
#pragma unroll
      for (int mt = 0; mt < 2; ++mt) {
        acc[mt][nt] = __builtin_amdgcn_mfma_scale_f32_16x16x128_f8f6f4(
            av[mt], bv, acc[mt][nt], 0, 0, 0, 127, 0, 127);
      }
    }

    if (it + 1 < iters) {
#pragma unroll
      for (int mt = 0; mt < 2; ++mt) bits_c[mt] = bits_n[mt];
    }
    __syncthreads();   // drains vmcnt(0): next tile landed; lgkmcnt(0): buf reads done
    cur ^= 1;
    itp = itn;
  }
#undef K2_STAGE

  // epilogue: x64 undoes the 2^-6 A-scale; per-wave LDS transpose -> panel chunks
  unsigned short* lw = (unsigned short*)((char*)lB[0] + w * 4608);
  float* oe = out2e + (size_t)ks * ((size_t)NN * 64);
  unsigned short* pb = out2b + ((size_t)(ks * 4 + cb) * NN + i0 + w * 32) * 144;
#pragma unroll
  for (int mt = 0; mt < 2; ++mt) {
#pragma unroll
    for (int nt = 0; nt < 9; ++nt) {
      const int coll = nt * 16 + lm;
#pragma unroll
      for (int rr = 0; rr < 4; ++rr)
        lw[(lk * 4 + rr) * 144 + coll] = f2bf(acc[mt][nt][rr] * 64.0f);
      if (cb == 3 && nt >= 5) {
        const int row = i0 + w * 32 + mt * 16 + lk * 4;
#pragma unroll
        for (int rr = 0; rr < 4; ++rr)
          oe[(size_t)(row + rr) * 64 + (n0 + coll - 512)] = acc[mt][nt][rr] * 64.0f;
      }
    }
    const uint4* ls = (const uint4*)((char*)lB[0] + w * 4608);
    char* dst = (char*)(pb + (size_t)mt * 16 * 144);
    for (int s = l; s < 288; s += 64)
      *(uint4*)(dst + s * 16) = ls[s];
  }
}

// ---------------- k3: combine across nks K-partials (R18-verified) ----------------
__global__ __launch_bounds__(256) void k3_final(
    const unsigned short* __restrict__ out2b, const float* __restrict__ out2e,
    const float* __restrict__ e_src, const float* __restrict__ T,
    float* __restrict__ out, int nks)
{
  const int n = blockIdx.x, c = threadIdx.x;
  const int h = c >> 6, d = c & 63;
  const int cS = h * 128 + d, cP = cS + 64;
  const int cbS = cS / 144, ofS = cS % 144;
  const int cbP = cP / 144, ofP = cP % 144;
  float Se = 0.f, Sp = 0.f, E = 0.f, dg = 0.f;
  for (int s = 0; s < nks; ++s) {
    const unsigned short* base = out2b + (size_t)s * 4 * NN * 144;
    Se += bf2f(base[((size_t)cbS * NN + n) * 144 + ofS]);
    Sp += bf2f(base[((size_t)cbP * NN + n) * 144 + ofP]);
    const float* re = out2e + (size_t)s * NN * 64 + (size_t)n * 64;
    E  += re[h];
    dg += re[4];
  }
  float e = e_src[h * NN + n];
  float D = e * E + ((float)NN - dg);
  out[(size_t)n * 256 + c] = (e * Se + (T[c] - Sp)) / D;
}

extern "C" void kernel_launch(void* const* d_in, const int* in_sizes, int n_in,
                              void* d_out, int out_size, void* d_ws, size_t ws_size,
                              hipStream_t stream) {
  const float* x  = (const float*)d_in[0];
  const int*   adj= (const int*)d_in[1];
  const float* W  = (const float*)d_in[2];
  const float* Wb = (const float*)d_in[3];
  const float* Aw = (const float*)d_in[4];
  const float* Ab = (const float*)d_in[5];
  float* out = (float*)d_out;
  char* ws = (char*)d_ws;
  unsigned char* V8 = (unsigned char*)ws;                 // 3,538,944
  float* e_src = (float*)(ws + 3538944);                  // 98,304
  float* T     = (float*)(ws + 3637248);                  // 1,024
  float* Acat  = (float*)(ws + 3638272);                  // 3,072 (asv|adv|Wbc)
  unsigned short* wsw = (unsigned short*)(ws + 3641344);  // 131,072
  unsigned* bm = (unsigned*)(ws + 6918144);               // 4,718,592 (adj bitmask)
  unsigned short* out2b = (unsigned short*)(ws + 44666880); // nks x 4 x 1,769,472 (panels)
  float* out2e = (float*)(ws + 87134208);                   // nks x 1,572,864

  const size_t slabB = (size_t)4 * NN * 144 * 2;   // 7,077,888 per ks
  const size_t slabE = (size_t)NN * 64 * 4;        // 1,572,864 per ks
  int nks = 2;
  if (ws_size >= 44666880 + 4 * slabB + 4 * slabE)  nks = 4;  // grid 768

  hipLaunchKernelGGL(p0s, dim3(9), dim3(256), 0, stream,
                     W, Aw, Wb, wsw, Acat, T);
  hipLaunchKernelGGL(k1m, dim3(4800), dim3(256), 0, stream,
                     x, wsw, Acat, Ab, adj, bm, V8, e_src, T);
  hipLaunchKernelGGL(k2_gemm, dim3(192 * nks), dim3(256), 0, stream, bm, V8, out2b, out2e, nks);
  hipLaunchKernelGGL(k3_final, dim3(NN), dim3(256), 0, stream, out2b, out2e, e_src, T, out, nks);
}